// Round 2
// baseline (184.255 us; speedup 1.0000x reference)
//
#include <hip/hip_runtime.h>
#include <math.h>

#define B_ 2
#define L_ 2048
#define H_ 16
#define E_ 64
#define D_ 64
#define DM_ 512
#define DH_ 256

typedef __bf16 bf16_t;
typedef bf16_t bf16x8_t __attribute__((ext_vector_type(8)));
typedef float f32x4_t __attribute__((ext_vector_type(4)));

// pack two floats to bf16x2 (round-up-at-halfway; 2 add + 1 perm)
__device__ __forceinline__ unsigned bpack(float hi, float lo) {
    unsigned uh = __float_as_uint(hi) + 0x8000u;
    unsigned ul = __float_as_uint(lo) + 0x8000u;
    return __builtin_amdgcn_perm(uh, ul, 0x07060302u);
}

__device__ __forceinline__ bf16_t to_bf16(float f) {
    union { float f; unsigned u; } x; x.f = f;
    unsigned r = (x.u + 0x7fffu + ((x.u >> 16) & 1u)) >> 16;
    union { unsigned short s; bf16_t b; } y; y.s = (unsigned short)r;
    return y.b;
}

// async 16B global->LDS copy; HW dest = (wave-uniform base) + lane*16
__device__ __forceinline__ void gload_lds16(const bf16_t* g, bf16_t* l) {
    __builtin_amdgcn_global_load_lds(
        (const __attribute__((address_space(1))) unsigned int*)g,
        (__attribute__((address_space(3))) unsigned int*)l, 16, 0, 0);
}

// K row permutation (makes swapped-QK^T S-values land in PV A-frag layout):
// p(s) = s[1:0] | s[3]<<2 | s[4]<<3 | s[2]<<4 | s[5]<<5
__device__ __forceinline__ int permK(int sl) {
    return (sl & 3) | (((sl >> 3) & 1) << 2) | (((sl >> 4) & 1) << 3)
         | (((sl >> 2) & 1) << 4) | (((sl >> 5) & 1) << 5);
}

// ---------------- prep: w1 transpose + K/V bf16 conversion -------------------
// blocks [0,256):    w1 [512][256] f32 -> w1t [256][512] bf16
// blocks [256,1280): K [b][s][h][e] f32 -> Kp [bh][tile][permK(sl)][e^swz] bf16
// blocks [1280,2304):V [b][s][h][d] f32 -> Vs [bh][d][tile*64 + (sl^swz)] bf16
// Both K and V get the attn LDS layout (incl. XOR bank swizzle) baked in, so
// attn staging is a pure linear 16B copy (global_load_lds-compatible).
__global__ __launch_bounds__(256) void prep_kernel(
        const float* __restrict__ w1, bf16_t* __restrict__ w1t,
        const float* __restrict__ K, bf16_t* __restrict__ Kp,
        const float* __restrict__ V, bf16_t* __restrict__ Vs) {
    __shared__ bf16_t T[64][88];       // V transpose tile (stride avoids conflicts)
    const int bidx = blockIdx.x;
    const int t = threadIdx.x;

    if (bidx < 256) {                  // ---- w1t ----
        const int n = bidx;
        #pragma unroll
        for (int u = 0; u < 2; ++u) {
            int k = t + u * 256;
            w1t[(size_t)n * DM_ + k] = to_bf16(w1[(size_t)k * DH_ + n]);
        }
        return;
    }

    if (bidx < 1280) {                 // ---- K convert ----
        const int idx = bidx - 256;
        const int bh = idx >> 5, tile = idx & 31;
        const int b = bh >> 4, h = bh & 15;
        const int sl = t >> 2, e0 = (t & 3) << 4;
        const float* src = K + (((size_t)b * L_ + tile * 64 + sl) * H_ + h) * E_ + e0;
        f32x4_t v0 = *(const f32x4_t*)(src);
        f32x4_t v1 = *(const f32x4_t*)(src + 4);
        f32x4_t v2 = *(const f32x4_t*)(src + 8);
        f32x4_t v3 = *(const f32x4_t*)(src + 12);
        uint4 lo, hi;
        lo.x = bpack(v0[1], v0[0]); lo.y = bpack(v0[3], v0[2]);
        lo.z = bpack(v1[1], v1[0]); lo.w = bpack(v1[3], v1[2]);
        hi.x = bpack(v2[1], v2[0]); hi.y = bpack(v2[3], v2[2]);
        hi.z = bpack(v3[1], v3[0]); hi.w = bpack(v3[3], v3[2]);
        const int r = permK(sl);
        const int bb = (r >> 3) & 7;
        bf16_t* drow = Kp + ((size_t)(bh * 32 + tile) * 64 + r) * 64;
        *(uint4*)(drow + ((((e0 >> 3)    ) ^ bb) << 3)) = lo;
        *(uint4*)(drow + ((((e0 >> 3) + 1) ^ bb) << 3)) = hi;
        return;
    }

    {                                  // ---- V convert/transpose ----
        const int idx = bidx - 1280;
        const int bh = idx >> 5, tile = idx & 31;
        const int b = bh >> 4, h = bh & 15;
        const int sl = t >> 2, d0 = (t & 3) << 4;
        const float* src = V + (((size_t)b * L_ + tile * 64 + sl) * H_ + h) * D_ + d0;
        f32x4_t v0 = *(const f32x4_t*)(src);
        f32x4_t v1 = *(const f32x4_t*)(src + 4);
        f32x4_t v2 = *(const f32x4_t*)(src + 8);
        f32x4_t v3 = *(const f32x4_t*)(src + 12);
        uint4 lo, hi;
        lo.x = bpack(v0[1], v0[0]); lo.y = bpack(v0[3], v0[2]);
        lo.z = bpack(v1[1], v1[0]); lo.w = bpack(v1[3], v1[2]);
        hi.x = bpack(v2[1], v2[0]); hi.y = bpack(v2[3], v2[2]);
        hi.z = bpack(v3[1], v3[0]); hi.w = bpack(v3[3], v3[2]);
        *(uint4*)&T[sl][d0]     = lo;
        *(uint4*)&T[sl][d0 + 8] = hi;
        __syncthreads();
        const int d = t & 63, bd = (d >> 3) & 7;
        bf16_t* drow = Vs + ((size_t)bh * 64 + d) * 2048 + tile * 64;
        #pragma unroll
        for (int gg = 0; gg < 2; ++gg) {
            int qb = (t >> 6) + gg * 4;
            int slb = (qb ^ bd) << 3;        // content(q) = V[q ^ (bd<<3)][d]
            union { unsigned short u[8]; uint4 q; } acc;
            #pragma unroll
            for (int j = 0; j < 8; ++j) {
                union { bf16_t b; unsigned short s; } x; x.b = T[slb + j][d];
                acc.u[j] = x.s;
            }
            *(uint4*)(drow + qb * 8) = acc.q;
        }
    }
}

// ---------------- MLP via MFMA: fused = relu(raw@w1+b1)@w2 + b2 --------------
__global__ __launch_bounds__(256) void mlp_kernel(
        const float* __restrict__ raw, const bf16_t* __restrict__ w1t,
        const float* __restrict__ b1, const float* __restrict__ w2,
        const float* __restrict__ b2, float* __restrict__ fused) {
    __shared__ bf16_t Rs[16][520];
    __shared__ float part[4][16];
    const int t = threadIdx.x;
    const int m0 = blockIdx.x * 16;
    #pragma unroll
    for (int u = 0; u < 8; ++u) {
        int idx = t + u * 256;
        int row = idx >> 7;
        int k = (idx & 127) << 2;
        f32x4_t v = *(const f32x4_t*)&raw[(size_t)(m0 + row) * DM_ + k];
        uint2 p;
        p.x = bpack(v[1], v[0]);
        p.y = bpack(v[3], v[2]);
        *(uint2*)&Rs[row][k] = p;
    }
    __syncthreads();
    const int wave = t >> 6;
    const int lane = t & 63;
    const int lrow = lane & 15;
    const int lgrp = lane >> 4;
    const int n0w = wave * 64;

    f32x4_t acc[4];
    #pragma unroll
    for (int nt = 0; nt < 4; ++nt) acc[nt] = (f32x4_t){0.f, 0.f, 0.f, 0.f};

    const bf16_t* wbase = w1t + (size_t)(n0w + lrow) * DM_ + lgrp * 8;
    #pragma unroll
    for (int s = 0; s < 16; ++s) {
        bf16x8_t a = *(const bf16x8_t*)&Rs[lrow][s * 32 + lgrp * 8];
        #pragma unroll
        for (int nt = 0; nt < 4; ++nt) {
            bf16x8_t b = *(const bf16x8_t*)(wbase + nt * 16 * DM_ + s * 32);
            acc[nt] = __builtin_amdgcn_mfma_f32_16x16x32_bf16(a, b, acc[nt], 0, 0, 0);
        }
    }
    float rowpart[4] = {0.f, 0.f, 0.f, 0.f};
    #pragma unroll
    for (int nt = 0; nt < 4; ++nt) {
        int n = n0w + nt * 16 + lrow;
        float b1v = b1[n];
        float w2v = w2[n];
        #pragma unroll
        for (int r = 0; r < 4; ++r) {
            float h = acc[nt][r] + b1v;
            h = h > 0.f ? h : 0.f;
            rowpart[r] += h * w2v;
        }
    }
    #pragma unroll
    for (int r = 0; r < 4; ++r) {
        float v = rowpart[r];
        v += __shfl_xor(v, 1);
        v += __shfl_xor(v, 2);
        v += __shfl_xor(v, 4);
        v += __shfl_xor(v, 8);
        if (lrow == 0) part[wave][lgrp * 4 + r] = v;
    }
    __syncthreads();
    if (t < 16)
        fused[m0 + t] = part[0][t] + part[1][t] + part[2][t] + part[3][t] + b2[0];
}

// ---------------- flash attention, async-staged pre-converted K/V -----------
// K/V arrive in the exact LDS layout (perm + XOR swizzle baked by prep), so
// staging = 4x global_load_lds per thread per step. Momentum computed inline
// from fused (diff). One barrier per step; double-buffered LDS.
__global__ __launch_bounds__(256) void attn_kernel(
        const float* __restrict__ Q, const bf16_t* __restrict__ Kp,
        const bf16_t* __restrict__ Vs, const float* __restrict__ fused,
        const float* __restrict__ alpha_trend, float* __restrict__ out) {
    __shared__ __align__(16) bf16_t Ks[2][64][64];
    __shared__ __align__(16) bf16_t Vt[2][64][64];
    __shared__ float moms[2][64];

    const int bid = blockIdx.x;
    const int bh  = bid & 31;
    const int grp = bid >> 5;
    // balanced pairing: consecutive 64-bid chunks hold qt {31-p, p} -> equal work
    const int qt  = (grp & 1) ? (grp >> 1) : 31 - (grp >> 1);
    const int h = bh & 15, b = bh >> 4;
    const int q0 = qt << 6;
    const int tid = threadIdx.x;
    const int wave = tid >> 6, lane = tid & 63;
    const int lrow = lane & 15, lgrp = lane >> 4;
    const int t8 = lrow >> 3;

    const float c1 = 0.18033688f;      // 0.125 * log2(e)
    const float ascale2 = alpha_trend[h] * c1;
    const size_t bl = (size_t)b * L_;
    const int qw0 = q0 + wave * 16;

    const bf16_t* Kb = Kp + (size_t)bh * 131072;   // 32 tiles * 4096 el
    const bf16_t* Vb = Vs + (size_t)bh * 131072;   // 64 rows * 2048 el
    const float* fusedp = fused + bl;

    // Q fragments, prescaled by c1 (RNE, once)
    bf16x8_t a_lo, a_hi;
    {
        const float* qp = Q + ((bl + qw0 + lrow) * H_ + h) * E_ + lgrp * 8;
        f32x4_t v0 = *(const f32x4_t*)(qp);
        f32x4_t v1 = *(const f32x4_t*)(qp + 4);
        f32x4_t v2 = *(const f32x4_t*)(qp + 32);
        f32x4_t v3 = *(const f32x4_t*)(qp + 36);
        #pragma unroll
        for (int k = 0; k < 4; ++k) {
            a_lo[k]     = to_bf16(v0[k] * c1);
            a_lo[4 + k] = to_bf16(v1[k] * c1);
            a_hi[k]     = to_bf16(v2[k] * c1);
            a_hi[4 + k] = to_bf16(v3[k] * c1);
        }
    }
    const int qg = qw0 + lrow;
    const float mq = (qg == 0) ? 0.f : fusedp[qg] - fusedp[qg - 1];

    // per-lane staging sources (global layout == LDS layout, linear copy)
    const bf16_t* ksrc = Kb + wave * 512 + lane * 8;
    const bf16_t* vsrc = Vb + (size_t)(wave * 8 + (lane >> 3)) * 2048 + (lane & 7) * 8;

    f32x4_t Oacc[4];
    #pragma unroll
    for (int c = 0; c < 4; ++c) Oacc[c] = (f32x4_t){0.f, 0.f, 0.f, 0.f};
    float rowsum = 0.f;

    auto stage = [&](int t) {
        const int nb = t & 1;
        const bf16_t* kp0 = ksrc + (size_t)t * 4096;
        gload_lds16(kp0,        &Ks[nb][wave * 8][0]);
        gload_lds16(kp0 + 2048, &Ks[nb][wave * 8 + 32][0]);
        const bf16_t* vp0 = vsrc + t * 64;
        gload_lds16(vp0,               &Vt[nb][wave * 8][0]);
        gload_lds16(vp0 + 32 * 2048,   &Vt[nb][wave * 8 + 32][0]);
        if (tid < 64) {                 // momentum tile (wave 0)
            int s = t * 64 + tid;
            float f = fusedp[s];
            float fm = __shfl_up(f, 1);
            if (tid == 0) fm = (s == 0) ? f : fusedp[s - 1];
            moms[nb][tid] = f - fm;
        }
    };

    stage(0);
    for (int st = 0; st <= qt; ++st) {
        const int buf = st & 1;
        __syncthreads();               // drains buf's async loads (vmcnt 0)
        if (st < qt) stage(st + 1);    // issue next tile; flies under compute

        const char* ksb = (const char*)&Ks[buf][0][0];
        const char* vtb = (const char*)&Vt[buf][0][0];

        // S^T = K Q^T (swapped operands; log2 domain via Q prescale)
        // lane holds S[q=qw0+lrow][s = 8*lgrp + 4*(c&1) + r + 32*(c>>1)]
        f32x4_t Sacc[4];
        #pragma unroll
        for (int c = 0; c < 4; ++c) Sacc[c] = (f32x4_t){0.f, 0.f, 0.f, 0.f};
        __builtin_amdgcn_s_setprio(1);
        #pragma unroll
        for (int c = 0; c < 4; ++c) {
            const char* kr = ksb + (c * 16 + lrow) * 128;
            const int bb = (c * 2 + t8) & 7;
            bf16x8_t k_lo = *(const bf16x8_t*)(kr + ((lgrp ^ bb) << 4));
            bf16x8_t k_hi = *(const bf16x8_t*)(kr + (((4 + lgrp) ^ bb) << 4));
            Sacc[c] = __builtin_amdgcn_mfma_f32_16x16x32_bf16(k_lo, a_lo, Sacc[c], 0, 0, 0);
            Sacc[c] = __builtin_amdgcn_mfma_f32_16x16x32_bf16(k_hi, a_hi, Sacc[c], 0, 0, 0);
        }
        __builtin_amdgcn_s_setprio(0);

        // P = exp2(S - ascale2*|dm|)
        float rowe[4][4];
        #pragma unroll
        for (int c = 0; c < 4; ++c) {
            const int sb = lgrp * 8 + ((c & 1) << 2) + ((c >> 1) << 5);
            f32x4_t ms4 = *(const f32x4_t*)&moms[buf][sb];
            #pragma unroll
            for (int r = 0; r < 4; ++r) {
                float arg = Sacc[c][r] - ascale2 * fabsf(mq - ms4[r]);
                rowe[c][r] = __builtin_amdgcn_exp2f(arg);
            }
        }
        if (st == qt) {                // causal mask on diagonal macro-tile
            const int s0 = st << 6;
            #pragma unroll
            for (int c = 0; c < 4; ++c) {
                const int sg0 = s0 + lgrp * 8 + ((c & 1) << 2) + ((c >> 1) << 5);
                #pragma unroll
                for (int r = 0; r < 4; ++r)
                    if (sg0 + r > qg) rowe[c][r] = 0.f;
            }
        }
        #pragma unroll
        for (int c = 0; c < 4; ++c)
            rowsum += (rowe[c][0] + rowe[c][1]) + (rowe[c][2] + rowe[c][3]);

        // O += P V : P fragments lane-local, pack to bf16
        #pragma unroll
        for (int hh = 0; hh < 2; ++hh) {
            union { unsigned u[4]; bf16x8_t v; } pa;
            pa.u[0] = bpack(rowe[2 * hh][1],     rowe[2 * hh][0]);
            pa.u[1] = bpack(rowe[2 * hh][3],     rowe[2 * hh][2]);
            pa.u[2] = bpack(rowe[2 * hh + 1][1], rowe[2 * hh + 1][0]);
            pa.u[3] = bpack(rowe[2 * hh + 1][3], rowe[2 * hh + 1][2]);
            __builtin_amdgcn_s_setprio(1);
            #pragma unroll
            for (int c2 = 0; c2 < 4; ++c2) {
                const int row = c2 * 16 + lrow;
                const int bb2 = (c2 * 2 + t8) & 7;
                bf16x8_t bv = *(const bf16x8_t*)(vtb + row * 128 +
                                                 (((hh * 4 + lgrp) ^ bb2) << 4));
                Oacc[c2] = __builtin_amdgcn_mfma_f32_16x16x32_bf16(pa.v, bv, Oacc[c2], 0, 0, 0);
            }
            __builtin_amdgcn_s_setprio(0);
        }
    }

    // epilogue: full row sums via 2 shuffles, normalize, store
    float rs = rowsum;
    rs += __shfl_xor(rs, 16);
    rs += __shfl_xor(rs, 32);
    #pragma unroll
    for (int r = 0; r < 4; ++r) {
        float inv = 1.f / __shfl(rs, lgrp * 4 + r);
        size_t orow = ((bl + qw0 + lgrp * 4 + r) * H_ + h) * D_;
        #pragma unroll
        for (int c = 0; c < 4; ++c)
            out[orow + c * 16 + lrow] = Oacc[c][r] * inv;
    }
}

extern "C" void kernel_launch(void* const* d_in, const int* in_sizes, int n_in,
                              void* d_out, int out_size, void* d_ws, size_t ws_size,
                              hipStream_t stream) {
    const float* Q     = (const float*)d_in[0];
    const float* K     = (const float*)d_in[1];
    const float* V     = (const float*)d_in[2];
    const float* raw   = (const float*)d_in[3];
    const float* w1    = (const float*)d_in[4];
    const float* b1    = (const float*)d_in[5];
    const float* w2    = (const float*)d_in[6];
    const float* b2    = (const float*)d_in[7];
    const float* alpha = (const float*)d_in[8];
    float* out = (float*)d_out;

    float* fused = (float*)d_ws;                       // 4096 f32
    bf16_t* w1t  = (bf16_t*)(fused + B_ * L_);         // 256*512 bf16
    bf16_t* Kp   = w1t + 256 * 512;                    // 8 MB
    bf16_t* Vs   = Kp + (size_t)B_ * H_ * L_ * E_;     // 8 MB

    prep_kernel<<<2304, 256, 0, stream>>>(w1, w1t, K, Kp, V, Vs);
    mlp_kernel<<<B_ * L_ / 16, 256, 0, stream>>>(raw, w1t, b1, w2, b2, fused);
    attn_kernel<<<B_ * H_ * (L_ / 64), 256, 0, stream>>>(Q, Kp, Vs, fused, alpha, out);
}

// Round 4
// 169.492 us; speedup vs baseline: 1.0871x; 1.0871x over previous
//
#include <hip/hip_runtime.h>
#include <math.h>

#define B_ 2
#define L_ 2048
#define H_ 16
#define E_ 64
#define D_ 64
#define DM_ 512
#define DH_ 256

typedef __bf16 bf16_t;
typedef bf16_t bf16x8_t __attribute__((ext_vector_type(8)));
typedef float f32x4_t __attribute__((ext_vector_type(4)));

// pack two floats to bf16x2 (round-up-at-halfway; 2 add + 1 perm)
__device__ __forceinline__ unsigned bpack(float hi, float lo) {
    unsigned uh = __float_as_uint(hi) + 0x8000u;
    unsigned ul = __float_as_uint(lo) + 0x8000u;
    return __builtin_amdgcn_perm(uh, ul, 0x07060302u);
}

__device__ __forceinline__ bf16_t to_bf16(float f) {
    union { float f; unsigned u; } x; x.f = f;
    unsigned r = (x.u + 0x7fffu + ((x.u >> 16) & 1u)) >> 16;
    union { unsigned short s; bf16_t b; } y; y.s = (unsigned short)r;
    return y.b;
}

// async 16B global->LDS copy; HW dest = (wave-uniform base) + lane*16
__device__ __forceinline__ void gload_lds16(const bf16_t* g, bf16_t* l) {
    __builtin_amdgcn_global_load_lds(
        (const __attribute__((address_space(1))) unsigned int*)g,
        (__attribute__((address_space(3))) unsigned int*)l, 16, 0, 0);
}

// K row permutation (makes swapped-QK^T S-values land in PV A-frag layout):
// p(s) = s[1:0] | s[3]<<2 | s[4]<<3 | s[2]<<4 | s[5]<<5
__device__ __forceinline__ int permK(int sl) {
    return (sl & 3) | (((sl >> 3) & 1) << 2) | (((sl >> 4) & 1) << 3)
         | (((sl >> 2) & 1) << 4) | (((sl >> 5) & 1) << 5);
}

// ---------------- prep: w1 transpose + K/V bf16 conversion -------------------
// blocks [0,256):    w1 [512][256] f32 -> w1t [256][512] bf16
// blocks [256,1280): K -> Kp [bh][tile][permK(sl)][slot^ (row&7) swizzle] bf16
// blocks [1280,2304):V -> Vs [bh][d][tile*64 + slot-swizzled s] bf16
// XOR swizzle uses the LOW 3 row bits (row&7): within a ds_read_b128 the
// colliding lanes differ in row&7, so this spreads them over all 8 16B slots.
__global__ __launch_bounds__(256) void prep_kernel(
        const float* __restrict__ w1, bf16_t* __restrict__ w1t,
        const float* __restrict__ K, bf16_t* __restrict__ Kp,
        const float* __restrict__ V, bf16_t* __restrict__ Vs) {
    __shared__ bf16_t T[64][88];       // V transpose tile (stride avoids conflicts)
    const int bidx = blockIdx.x;
    const int t = threadIdx.x;

    if (bidx < 256) {                  // ---- w1t ----
        const int n = bidx;
        #pragma unroll
        for (int u = 0; u < 2; ++u) {
            int k = t + u * 256;
            w1t[(size_t)n * DM_ + k] = to_bf16(w1[(size_t)k * DH_ + n]);
        }
        return;
    }

    if (bidx < 1280) {                 // ---- K convert ----
        const int idx = bidx - 256;
        const int bh = idx >> 5, tile = idx & 31;
        const int b = bh >> 4, h = bh & 15;
        const int sl = t >> 2, e0 = (t & 3) << 4;
        const float* src = K + (((size_t)b * L_ + tile * 64 + sl) * H_ + h) * E_ + e0;
        f32x4_t v0 = *(const f32x4_t*)(src);
        f32x4_t v1 = *(const f32x4_t*)(src + 4);
        f32x4_t v2 = *(const f32x4_t*)(src + 8);
        f32x4_t v3 = *(const f32x4_t*)(src + 12);
        uint4 lo, hi;
        lo.x = bpack(v0[1], v0[0]); lo.y = bpack(v0[3], v0[2]);
        lo.z = bpack(v1[1], v1[0]); lo.w = bpack(v1[3], v1[2]);
        hi.x = bpack(v2[1], v2[0]); hi.y = bpack(v2[3], v2[2]);
        hi.z = bpack(v3[1], v3[0]); hi.w = bpack(v3[3], v3[2]);
        const int r = permK(sl);
        const int bb = r & 7;          // low row bits -> bank spread
        bf16_t* drow = Kp + ((size_t)(bh * 32 + tile) * 64 + r) * 64;
        *(uint4*)(drow + ((((e0 >> 3)    ) ^ bb) << 3)) = lo;
        *(uint4*)(drow + ((((e0 >> 3) + 1) ^ bb) << 3)) = hi;
        return;
    }

    {                                  // ---- V convert/transpose ----
        const int idx = bidx - 1280;
        const int bh = idx >> 5, tile = idx & 31;
        const int b = bh >> 4, h = bh & 15;
        const int sl = t >> 2, d0 = (t & 3) << 4;
        const float* src = V + (((size_t)b * L_ + tile * 64 + sl) * H_ + h) * D_ + d0;
        f32x4_t v0 = *(const f32x4_t*)(src);
        f32x4_t v1 = *(const f32x4_t*)(src + 4);
        f32x4_t v2 = *(const f32x4_t*)(src + 8);
        f32x4_t v3 = *(const f32x4_t*)(src + 12);
        uint4 lo, hi;
        lo.x = bpack(v0[1], v0[0]); lo.y = bpack(v0[3], v0[2]);
        lo.z = bpack(v1[1], v1[0]); lo.w = bpack(v1[3], v1[2]);
        hi.x = bpack(v2[1], v2[0]); hi.y = bpack(v2[3], v2[2]);
        hi.z = bpack(v3[1], v3[0]); hi.w = bpack(v3[3], v3[2]);
        *(uint4*)&T[sl][d0]     = lo;
        *(uint4*)&T[sl][d0 + 8] = hi;
        __syncthreads();
        const int d = t & 63, bd = d & 7;  // low row bits -> bank spread
        bf16_t* drow = Vs + ((size_t)bh * 64 + d) * 2048 + tile * 64;
        #pragma unroll
        for (int gg = 0; gg < 2; ++gg) {
            int qb = (t >> 6) + gg * 4;
            int slb = (qb ^ bd) << 3;        // content(slot q) = V[(q^bd)*8+j][d]
            union { unsigned short u[8]; uint4 q; } acc;
            #pragma unroll
            for (int j = 0; j < 8; ++j) {
                union { bf16_t b; unsigned short s; } x; x.b = T[slb + j][d];
                acc.u[j] = x.s;
            }
            *(uint4*)(drow + qb * 8) = acc.q;
        }
    }
}

// ---------------- MLP via MFMA: fused = relu(raw@w1+b1)@w2 + b2 --------------
__global__ __launch_bounds__(256) void mlp_kernel(
        const float* __restrict__ raw, const bf16_t* __restrict__ w1t,
        const float* __restrict__ b1, const float* __restrict__ w2,
        const float* __restrict__ b2, float* __restrict__ fused) {
    __shared__ bf16_t Rs[16][520];
    __shared__ float part[4][16];
    const int t = threadIdx.x;
    const int m0 = blockIdx.x * 16;
    #pragma unroll
    for (int u = 0; u < 8; ++u) {
        int idx = t + u * 256;
        int row = idx >> 7;
        int k = (idx & 127) << 2;
        f32x4_t v = *(const f32x4_t*)&raw[(size_t)(m0 + row) * DM_ + k];
        uint2 p;
        p.x = bpack(v[1], v[0]);
        p.y = bpack(v[3], v[2]);
        *(uint2*)&Rs[row][k] = p;
    }
    __syncthreads();
    const int wave = t >> 6;
    const int lane = t & 63;
    const int lrow = lane & 15;
    const int lgrp = lane >> 4;
    const int n0w = wave * 64;

    f32x4_t acc[4];
    #pragma unroll
    for (int nt = 0; nt < 4; ++nt) acc[nt] = (f32x4_t){0.f, 0.f, 0.f, 0.f};

    const bf16_t* wbase = w1t + (size_t)(n0w + lrow) * DM_ + lgrp * 8;
    #pragma unroll
    for (int s = 0; s < 16; ++s) {
        bf16x8_t a = *(const bf16x8_t*)&Rs[lrow][s * 32 + lgrp * 8];
        #pragma unroll
        for (int nt = 0; nt < 4; ++nt) {
            bf16x8_t b = *(const bf16x8_t*)(wbase + nt * 16 * DM_ + s * 32);
            acc[nt] = __builtin_amdgcn_mfma_f32_16x16x32_bf16(a, b, acc[nt], 0, 0, 0);
        }
    }
    float rowpart[4] = {0.f, 0.f, 0.f, 0.f};
    #pragma unroll
    for (int nt = 0; nt < 4; ++nt) {
        int n = n0w + nt * 16 + lrow;
        float b1v = b1[n];
        float w2v = w2[n];
        #pragma unroll
        for (int r = 0; r < 4; ++r) {
            float h = acc[nt][r] + b1v;
            h = h > 0.f ? h : 0.f;
            rowpart[r] += h * w2v;
        }
    }
    #pragma unroll
    for (int r = 0; r < 4; ++r) {
        float v = rowpart[r];
        v += __shfl_xor(v, 1);
        v += __shfl_xor(v, 2);
        v += __shfl_xor(v, 4);
        v += __shfl_xor(v, 8);
        if (lrow == 0) part[wave][lgrp * 4 + r] = v;
    }
    __syncthreads();
    if (t < 16)
        fused[m0 + t] = part[0][t] + part[1][t] + part[2][t] + part[3][t] + b2[0];
}

// ---------------- flash attention, async-staged pre-converted K/V -----------
// K/V arrive in the exact LDS layout (perm + row&7 XOR swizzle baked by prep),
// so staging = 4x global_load_lds per thread per step; all ds_read_b128 are
// bank-conflict-free. One barrier per step; double-buffered LDS.
__global__ __launch_bounds__(256) void attn_kernel(
        const float* __restrict__ Q, const bf16_t* __restrict__ Kp,
        const bf16_t* __restrict__ Vs, const float* __restrict__ fused,
        const float* __restrict__ alpha_trend, float* __restrict__ out) {
    __shared__ __align__(16) bf16_t Ks[2][64][64];
    __shared__ __align__(16) bf16_t Vt[2][64][64];
    __shared__ float moms[2][64];

    const int bid = blockIdx.x;
    const int bh  = bid & 31;
    const int grp = bid >> 5;
    // balanced pairing: consecutive 64-bid chunks hold qt {31-p, p} -> equal work
    const int qt  = (grp & 1) ? (grp >> 1) : 31 - (grp >> 1);
    const int h = bh & 15, b = bh >> 4;
    const int q0 = qt << 6;
    const int tid = threadIdx.x;
    const int wave = tid >> 6, lane = tid & 63;
    const int lrow = lane & 15, lgrp = lane >> 4;

    const float c1 = 0.18033688f;      // 0.125 * log2(e)
    const float ascale2 = alpha_trend[h] * c1;
    const size_t bl = (size_t)b * L_;
    const int qw0 = q0 + wave * 16;

    const bf16_t* Kb = Kp + (size_t)bh * 131072;   // 32 tiles * 4096 el
    const bf16_t* Vb = Vs + (size_t)bh * 131072;   // 64 rows * 2048 el
    const float* fusedp = fused + bl;

    // Q fragments, prescaled by c1 (RNE, once)
    bf16x8_t a_lo, a_hi;
    {
        const float* qp = Q + ((bl + qw0 + lrow) * H_ + h) * E_ + lgrp * 8;
        f32x4_t v0 = *(const f32x4_t*)(qp);
        f32x4_t v1 = *(const f32x4_t*)(qp + 4);
        f32x4_t v2 = *(const f32x4_t*)(qp + 32);
        f32x4_t v3 = *(const f32x4_t*)(qp + 36);
        #pragma unroll
        for (int k = 0; k < 4; ++k) {
            a_lo[k]     = to_bf16(v0[k] * c1);
            a_lo[4 + k] = to_bf16(v1[k] * c1);
            a_hi[k]     = to_bf16(v2[k] * c1);
            a_hi[4 + k] = to_bf16(v3[k] * c1);
        }
    }
    const int qg = qw0 + lrow;
    const float mq = (qg == 0) ? 0.f : fusedp[qg] - fusedp[qg - 1];

    // per-lane staging sources (global layout == LDS layout, linear copy)
    const bf16_t* ksrc = Kb + wave * 512 + lane * 8;
    const bf16_t* vsrc = Vb + (size_t)(wave * 8 + (lane >> 3)) * 2048 + (lane & 7) * 8;

    f32x4_t Oacc[4];
    #pragma unroll
    for (int c = 0; c < 4; ++c) Oacc[c] = (f32x4_t){0.f, 0.f, 0.f, 0.f};
    float rowsum = 0.f;

    auto stage = [&](int t) {
        const int nb = t & 1;
        const bf16_t* kp0 = ksrc + (size_t)t * 4096;
        gload_lds16(kp0,        &Ks[nb][wave * 8][0]);
        gload_lds16(kp0 + 2048, &Ks[nb][wave * 8 + 32][0]);
        const bf16_t* vp0 = vsrc + t * 64;
        gload_lds16(vp0,               &Vt[nb][wave * 8][0]);
        gload_lds16(vp0 + 32 * 2048,   &Vt[nb][wave * 8 + 32][0]);
        if (tid < 64) {                 // momentum tile (wave 0)
            int s = t * 64 + tid;
            float f = fusedp[s];
            float fm = __shfl_up(f, 1);
            if (tid == 0) fm = (s == 0) ? f : fusedp[s - 1];
            moms[nb][tid] = f - fm;
        }
    };

    stage(0);
    for (int st = 0; st <= qt; ++st) {
        const int buf = st & 1;
        __syncthreads();               // drains buf's async loads (vmcnt 0)
        if (st < qt) stage(st + 1);    // issue next tile; flies under compute

        const char* ksb = (const char*)&Ks[buf][0][0];
        const char* vtb = (const char*)&Vt[buf][0][0];
        const int bb = lrow & 7;       // read-side swizzle (matches prep)

        // S^T = K Q^T (swapped operands; log2 domain via Q prescale)
        // lane holds S[q=qw0+lrow][s = 8*lgrp + 4*(c&1) + r + 32*(c>>1)]
        f32x4_t Sacc[4];
        #pragma unroll
        for (int c = 0; c < 4; ++c) Sacc[c] = (f32x4_t){0.f, 0.f, 0.f, 0.f};
        __builtin_amdgcn_s_setprio(1);
        #pragma unroll
        for (int c = 0; c < 4; ++c) {
            const char* kr = ksb + (c * 16 + lrow) * 128;
            bf16x8_t k_lo = *(const bf16x8_t*)(kr + ((lgrp ^ bb) << 4));
            bf16x8_t k_hi = *(const bf16x8_t*)(kr + (((4 + lgrp) ^ bb) << 4));
            Sacc[c] = __builtin_amdgcn_mfma_f32_16x16x32_bf16(k_lo, a_lo, Sacc[c], 0, 0, 0);
            Sacc[c] = __builtin_amdgcn_mfma_f32_16x16x32_bf16(k_hi, a_hi, Sacc[c], 0, 0, 0);
        }
        __builtin_amdgcn_s_setprio(0);

        // P = exp2(S - ascale2*|dm|)
        float rowe[4][4];
        #pragma unroll
        for (int c = 0; c < 4; ++c) {
            const int sb = lgrp * 8 + ((c & 1) << 2) + ((c >> 1) << 5);
            f32x4_t ms4 = *(const f32x4_t*)&moms[buf][sb];
            #pragma unroll
            for (int r = 0; r < 4; ++r) {
                float arg = Sacc[c][r] - ascale2 * fabsf(mq - ms4[r]);
                rowe[c][r] = __builtin_amdgcn_exp2f(arg);
            }
        }
        if (st == qt) {                // causal mask on diagonal macro-tile
            const int s0 = st << 6;
            #pragma unroll
            for (int c = 0; c < 4; ++c) {
                const int sg0 = s0 + lgrp * 8 + ((c & 1) << 2) + ((c >> 1) << 5);
                #pragma unroll
                for (int r = 0; r < 4; ++r)
                    if (sg0 + r > qg) rowe[c][r] = 0.f;
            }
        }
        #pragma unroll
        for (int c = 0; c < 4; ++c)
            rowsum += (rowe[c][0] + rowe[c][1]) + (rowe[c][2] + rowe[c][3]);

        // O += P V : P fragments lane-local, pack to bf16
        #pragma unroll
        for (int hh = 0; hh < 2; ++hh) {
            union { unsigned u[4]; bf16x8_t v; } pa;
            pa.u[0] = bpack(rowe[2 * hh][1],     rowe[2 * hh][0]);
            pa.u[1] = bpack(rowe[2 * hh][3],     rowe[2 * hh][2]);
            pa.u[2] = bpack(rowe[2 * hh + 1][1], rowe[2 * hh + 1][0]);
            pa.u[3] = bpack(rowe[2 * hh + 1][3], rowe[2 * hh + 1][2]);
            __builtin_amdgcn_s_setprio(1);
            #pragma unroll
            for (int c2 = 0; c2 < 4; ++c2) {
                const int row = c2 * 16 + lrow;
                bf16x8_t bv = *(const bf16x8_t*)(vtb + row * 128 +
                                                 (((hh * 4 + lgrp) ^ bb) << 4));
                Oacc[c2] = __builtin_amdgcn_mfma_f32_16x16x32_bf16(pa.v, bv, Oacc[c2], 0, 0, 0);
            }
            __builtin_amdgcn_s_setprio(0);
        }
    }

    // epilogue: full row sums via 2 shuffles, normalize, store
    float rs = rowsum;
    rs += __shfl_xor(rs, 16);
    rs += __shfl_xor(rs, 32);
    #pragma unroll
    for (int r = 0; r < 4; ++r) {
        float inv = 1.f / __shfl(rs, lgrp * 4 + r);
        size_t orow = ((bl + qw0 + lgrp * 4 + r) * H_ + h) * D_;
        #pragma unroll
        for (int c = 0; c < 4; ++c)
            out[orow + c * 16 + lrow] = Oacc[c][r] * inv;
    }
}

extern "C" void kernel_launch(void* const* d_in, const int* in_sizes, int n_in,
                              void* d_out, int out_size, void* d_ws, size_t ws_size,
                              hipStream_t stream) {
    const float* Q     = (const float*)d_in[0];
    const float* K     = (const float*)d_in[1];
    const float* V     = (const float*)d_in[2];
    const float* raw   = (const float*)d_in[3];
    const float* w1    = (const float*)d_in[4];
    const float* b1    = (const float*)d_in[5];
    const float* w2    = (const float*)d_in[6];
    const float* b2    = (const float*)d_in[7];
    const float* alpha = (const float*)d_in[8];
    float* out = (float*)d_out;

    float* fused = (float*)d_ws;                       // 4096 f32
    bf16_t* w1t  = (bf16_t*)(fused + B_ * L_);         // 256*512 bf16
    bf16_t* Kp   = w1t + 256 * 512;                    // 8 MB
    bf16_t* Vs   = Kp + (size_t)B_ * H_ * L_ * E_;     // 8 MB

    prep_kernel<<<2304, 256, 0, stream>>>(w1, w1t, K, Kp, V, Vs);
    mlp_kernel<<<B_ * L_ / 16, 256, 0, stream>>>(raw, w1t, b1, w2, b2, fused);
    attn_kernel<<<B_ * H_ * (L_ / 64), 256, 0, stream>>>(Q, Kp, Vs, fused, alpha, out);
}